// Round 4
// baseline (606.532 us; speedup 1.0000x reference)
//
#include <hip/hip_runtime.h>
#include <hip/hip_bf16.h>
#include <stdint.h>

#define N_NODES   65536
#define N_GRAPHS  1024
#define N_EDGES   1048576
#define IN_FEATS  512
#define HIDDEN    1024
#define H4        256
#define EMB_DIM   512
#define RDIM      1792   // 512 + 1024 + 256
#define EPS_F     1e-5f
#define SLOPE_F   0.01f

typedef __bf16 bf16;
typedef __bf16 bf16x8 __attribute__((ext_vector_type(8)));
typedef float  floatx4 __attribute__((ext_vector_type(4)));

#define GLDS16(gp, lp) __builtin_amdgcn_global_load_lds( \
    (const __attribute__((address_space(1))) void*)(gp), \
    (__attribute__((address_space(3))) void*)(lp), 16, 0, 0)

#define MFMA16(a, b, c) __builtin_amdgcn_mfma_f32_16x16x32_bf16((a), (b), (c), 0, 0, 0)

// -------------------------------------------- fused edge pass, per graph
__global__ __launch_bounds__(256) void k_graph_build(
    const int* __restrict__ src, const int* __restrict__ dst,
    const float* __restrict__ ew,
    bf16* __restrict__ adjb, float* __restrict__ scl_o)
{
    __shared__ float sAdj[4096];
    __shared__ float sDegO[64], sDegI[64];
    int g = blockIdx.x, tid = threadIdx.x;
    for (int i = tid; i < 4096; i += 256) sAdj[i] = 0.f;
    if (tid < 64) { sDegO[tid] = 0.f; sDegI[tid] = 0.f; }
    __syncthreads();
    int e0 = g * 1024;
    #pragma unroll
    for (int i = 0; i < 4; ++i) {
        int e = e0 + i * 256 + tid;
        int s = src[e] & 63, d = dst[e] & 63;
        atomicAdd(&sAdj[(d << 6) | s], ew[e]);
        atomicAdd(&sDegO[s], 1.f);
        atomicAdd(&sDegI[d], 1.f);
    }
    __syncthreads();
    if (tid < 64) scl_o[g * 64 + tid] = rsqrtf(fmaxf(sDegO[tid], 1.f));
    bf16* ag = adjb + ((size_t)g << 12);
    for (int i = tid; i < 4096; i += 256) {
        float si = rsqrtf(fmaxf(sDegI[i >> 6], 1.f));
        ag[i] = (bf16)(sAdj[i] * si);
    }
}

// W[K][N] -> WT[N][K] bf16
__global__ __launch_bounds__(256) void k_transpose(
    const float* __restrict__ W, bf16* __restrict__ WT, int K, int logN)
{
    int idx = blockIdx.x * 256 + threadIdx.x;
    if (idx >= (K << logN)) return;
    int n = idx & ((1 << logN) - 1);
    int k = idx >> logN;
    WT[(size_t)n * K + k] = (bf16)W[idx];
}

// -------------------------------------- fused prep + agg layer 1 (2 blk/graph)
__global__ __launch_bounds__(256) void k_prep_agg1(
    const float* __restrict__ x, const float* __restrict__ so,
    const bf16* __restrict__ adjb,
    bf16* __restrict__ axs1, bf16* __restrict__ Rb)
{
    __shared__ __align__(16) bf16 sOut[64 * 264];
    __shared__ float sSo[64];
    int g = blockIdx.x >> 1, half = blockIdx.x & 1;
    int tid = threadIdx.x, lane = tid & 63, wave = tid >> 6, q = lane >> 4;
    if (tid < 64) sSo[tid] = so[g * 64 + tid];
    const float* xg = x + (size_t)g * 64 * IN_FEATS + half * 256;
    const bf16* ag = adjb + ((size_t)g << 12);

    bf16x8 af[4][2];
    #pragma unroll
    for (int mt = 0; mt < 4; ++mt)
        #pragma unroll
        for (int kk = 0; kk < 2; ++kk)
            af[mt][kk] = *(const bf16x8*)&ag[(mt * 16 + (lane & 15)) * 64 + kk * 32 + q * 8];
    __syncthreads();
    float sov[2][8];
    #pragma unroll
    for (int kk = 0; kk < 2; ++kk)
        #pragma unroll
        for (int j = 0; j < 8; ++j) sov[kk][j] = sSo[kk * 32 + q * 8 + j];

    #pragma unroll
    for (int nt = 0; nt < 4; ++nt) {
        int cl = wave * 64 + nt * 16 + (lane & 15);
        floatx4 acc[4] = {};
        float r0 = 0.f;
        #pragma unroll
        for (int kk = 0; kk < 2; ++kk) {
            bf16x8 bfrag;
            #pragma unroll
            for (int j = 0; j < 8; ++j) {
                float v = xg[(size_t)(kk * 32 + q * 8 + j) * IN_FEATS + cl];
                r0 += v;
                bfrag[j] = (bf16)(v * sov[kk][j]);
            }
            #pragma unroll
            for (int mt = 0; mt < 4; ++mt)
                acc[mt] = MFMA16(af[mt][kk], bfrag, acc[mt]);
        }
        r0 += __shfl_xor(r0, 16);
        r0 += __shfl_xor(r0, 32);
        if (lane < 16) Rb[(size_t)g * RDIM + half * 256 + cl] = (bf16)(r0 * (1.f / 64.f));
        #pragma unroll
        for (int mt = 0; mt < 4; ++mt)
            #pragma unroll
            for (int i = 0; i < 4; ++i)
                sOut[(mt * 16 + q * 4 + i) * 264 + cl] = (bf16)acc[mt][i];
    }
    __syncthreads();
    #pragma unroll
    for (int it = 0; it < 8; ++it) {
        int idx = it * 256 + tid;
        int d = idx >> 5, c8 = idx & 31;
        *(bf16x8*)&axs1[(size_t)(g * 64 + d) * IN_FEATS + half * 256 + c8 * 8] =
            *(const bf16x8*)&sOut[d * 264 + c8 * 8];
    }
}

// -------------------------------------------------------- fused layers 1+2
// One block per graph. A = axs1[g] (64x512) resident in LDS (XOR-swizzled),
// W1T/W2T streamed from global (L2-resident). Layer-2 accumulates in VGPRs;
// xs2/h2 never touch global memory.
__global__ __launch_bounds__(256) void k_fused12(
    const bf16* __restrict__ axs1, const bf16* __restrict__ W1T,
    const bf16* __restrict__ W2T,  const bf16* __restrict__ adjb,
    const float* __restrict__ so,
    const float* __restrict__ a1v, const float* __restrict__ g1v,
    const float* __restrict__ b1v,
    const float* __restrict__ a2v, const float* __restrict__ g2v,
    const float* __restrict__ b2v,
    bf16* __restrict__ Rb)
{
    __shared__ __align__(16) bf16 sm[40960];          // 80 KB total
    bf16* sA = sm;            // [64 r][64 units], unit c stored at c^(r&63)
    bf16* sX = sm + 32768;    // [64 r][16 units], unit c stored at c^(r&15)

    const int g = blockIdx.x, tid = threadIdx.x;
    const int lane = tid & 63, wave = tid >> 6, q = lane >> 4, l15 = lane & 15;

    // ---- stage A once (4096 16B units, 16 per thread)
    const bf16* Ag = axs1 + (((size_t)g << 6) * IN_FEATS);
    #pragma unroll
    for (int i = 0; i < 16; ++i) {
        int u = i * 256 + tid;
        int r = u >> 6, cp = u & 63;
        int c = cp ^ (r & 63);
        GLDS16(Ag + ((size_t)r << 9) + (c << 3), &sA[(i * 256 + wave * 64) * 8]);
    }
    // rsqrt(deg_out) for the 16 rows this lane's C-fragments touch
    float sov[16];
    #pragma unroll
    for (int mt = 0; mt < 4; ++mt)
        #pragma unroll
        for (int i = 0; i < 4; ++i)
            sov[mt * 4 + i] = so[g * 64 + mt * 16 + q * 4 + i];

    floatx4 h2[4][4] = {};    // layer-2 acc: 64 rows x cols [wave*64, wave*64+64)

    asm volatile("s_waitcnt vmcnt(0)" ::: "memory");
    __syncthreads();

    for (int c = 0; c < 8; ++c) {                     // 128-col chunks of HIDDEN
        floatx4 acc[4][2] = {};
        // ---- layer-1 K-loop: no barriers (A in LDS, B from global/L2)
        #pragma unroll 4
        for (int ks = 0; ks < 16; ++ks) {
            bf16x8 bfr[2];
            #pragma unroll
            for (int nt = 0; nt < 2; ++nt) {
                int n = c * 128 + wave * 32 + nt * 16 + l15;
                bfr[nt] = *(const bf16x8*)&W1T[((size_t)n << 9) + ks * 32 + q * 8];
            }
            bf16x8 afr[4];
            #pragma unroll
            for (int mt = 0; mt < 4; ++mt) {
                int r = mt * 16 + l15;
                int cu = (ks * 4 + q) ^ (r & 63);
                afr[mt] = *(const bf16x8*)&sA[(r * 64 + cu) * 8];
            }
            #pragma unroll
            for (int mt = 0; mt < 4; ++mt)
                #pragma unroll
                for (int nt = 0; nt < 2; ++nt)
                    acc[mt][nt] = MFMA16(afr[mt], bfr[nt], acc[mt][nt]);
        }
        // ---- GraphNorm1 + leaky + r1 + xs2-chunk to LDS
        #pragma unroll
        for (int nt = 0; nt < 2; ++nt) {
            int cl = wave * 32 + nt * 16 + l15;       // col in chunk (0..127)
            int colg = c * 128 + cl;
            float lsum = 0.f;
            #pragma unroll
            for (int mt = 0; mt < 4; ++mt)
                #pragma unroll
                for (int i = 0; i < 4; ++i) lsum += acc[mt][nt][i];
            lsum += __shfl_xor(lsum, 16);
            lsum += __shfl_xor(lsum, 32);
            float am = a1v[colg] * (lsum * (1.f / 64.f));
            float gm = g1v[colg], bt = b1v[colg];
            float sub[4][4], qv = 0.f;
            #pragma unroll
            for (int mt = 0; mt < 4; ++mt)
                #pragma unroll
                for (int i = 0; i < 4; ++i) {
                    float d = acc[mt][nt][i] - am;
                    sub[mt][i] = d; qv += d * d;
                }
            qv += __shfl_xor(qv, 16);
            qv += __shfl_xor(qv, 32);
            float rs = rsqrtf(qv * (1.f / 64.f) + EPS_F);
            float rsum = 0.f;
            int cu = cl >> 3, ce = cl & 7;
            #pragma unroll
            for (int mt = 0; mt < 4; ++mt)
                #pragma unroll
                for (int i = 0; i < 4; ++i) {
                    float o = gm * sub[mt][i] * rs + bt;
                    o = (o >= 0.f) ? o : SLOPE_F * o;
                    rsum += o;
                    int r = mt * 16 + q * 4 + i;
                    sX[(r * 16 + (cu ^ (r & 15))) * 8 + ce] = (bf16)(o * sov[mt * 4 + i]);
                }
            rsum += __shfl_xor(rsum, 16);
            rsum += __shfl_xor(rsum, 32);
            if (lane < 16)
                Rb[(size_t)g * RDIM + 512 + colg] = (bf16)(rsum * (1.f / 64.f));
        }
        __syncthreads();
        // ---- layer-2 partial: h2 += xs2chunk(64x128) @ W2[c*128..+128, :]
        #pragma unroll
        for (int kk = 0; kk < 4; ++kk) {
            bf16x8 afr[4], bfr[4];
            #pragma unroll
            for (int mt = 0; mt < 4; ++mt) {
                int r = mt * 16 + l15;
                int cu = (kk * 4 + q) ^ (r & 15);
                afr[mt] = *(const bf16x8*)&sX[(r * 16 + cu) * 8];
            }
            #pragma unroll
            for (int nt = 0; nt < 4; ++nt) {
                int n = wave * 64 + nt * 16 + l15;
                bfr[nt] = *(const bf16x8*)&W2T[((size_t)n << 10) + c * 128 + kk * 32 + q * 8];
            }
            #pragma unroll
            for (int mt = 0; mt < 4; ++mt)
                #pragma unroll
                for (int nt = 0; nt < 4; ++nt)
                    h2[mt][nt] = MFMA16(afr[mt], bfr[nt], h2[mt][nt]);
        }
        __syncthreads();
    }

    // ---- aggregation: h2agg = adj_g @ h2pre (wave-local via LDS transpose)
    bf16* sT = sA + wave * (64 * 68);                 // [col 64][node pitch 68]
    #pragma unroll
    for (int nt = 0; nt < 4; ++nt) {
        int cl = nt * 16 + l15;
        #pragma unroll
        for (int mt = 0; mt < 4; ++mt)
            #pragma unroll
            for (int i = 0; i < 4; ++i)
                sT[cl * 68 + mt * 16 + q * 4 + i] = (bf16)h2[mt][nt][i];
    }
    asm volatile("s_waitcnt lgkmcnt(0)" ::: "memory");  // wave-local LDS RAW
    const bf16* ag = adjb + ((size_t)g << 12);
    floatx4 fin[4][4] = {};
    #pragma unroll
    for (int kk = 0; kk < 2; ++kk) {
        bf16x8 afr[4], bfr[4];
        #pragma unroll
        for (int mt = 0; mt < 4; ++mt)
            afr[mt] = *(const bf16x8*)&ag[(mt * 16 + l15) * 64 + kk * 32 + q * 8];
        #pragma unroll
        for (int nt = 0; nt < 4; ++nt)
            bfr[nt] = *(const bf16x8*)&sT[(nt * 16 + l15) * 68 + kk * 32 + q * 8];
        #pragma unroll
        for (int mt = 0; mt < 4; ++mt)
            #pragma unroll
            for (int nt = 0; nt < 4; ++nt)
                fin[mt][nt] = MFMA16(afr[mt], bfr[nt], fin[mt][nt]);
    }
    // ---- GraphNorm2 + leaky + r2
    #pragma unroll
    for (int nt = 0; nt < 4; ++nt) {
        int colg = wave * 64 + nt * 16 + l15;         // 0..255
        float lsum = 0.f;
        #pragma unroll
        for (int mt = 0; mt < 4; ++mt)
            #pragma unroll
            for (int i = 0; i < 4; ++i) lsum += fin[mt][nt][i];
        lsum += __shfl_xor(lsum, 16);
        lsum += __shfl_xor(lsum, 32);
        float am = a2v[colg] * (lsum * (1.f / 64.f));
        float gm = g2v[colg], bt = b2v[colg];
        float sub[4][4], qv = 0.f;
        #pragma unroll
        for (int mt = 0; mt < 4; ++mt)
            #pragma unroll
            for (int i = 0; i < 4; ++i) {
                float d = fin[mt][nt][i] - am;
                sub[mt][i] = d; qv += d * d;
            }
        qv += __shfl_xor(qv, 16);
        qv += __shfl_xor(qv, 32);
        float rs = rsqrtf(qv * (1.f / 64.f) + EPS_F);
        float rsum = 0.f;
        #pragma unroll
        for (int mt = 0; mt < 4; ++mt)
            #pragma unroll
            for (int i = 0; i < 4; ++i) {
                float o = gm * sub[mt][i] * rs + bt;
                rsum += (o >= 0.f) ? o : SLOPE_F * o;
            }
        rsum += __shfl_xor(rsum, 16);
        rsum += __shfl_xor(rsum, 32);
        if (lane < 16)
            Rb[(size_t)g * RDIM + 1536 + colg] = (bf16)(rsum * (1.f / 64.f));
    }
}

// ----------------------------------------------------- shared GEMM main loop
__device__ __forceinline__ void gemm_mainloop(
    const bf16* __restrict__ A, const bf16* __restrict__ BT, int K,
    int row0, int col0, int lane, int wave, int wm, int wn, int q,
    bf16* sA, bf16* sB, floatx4 (&acc)[4][4])
{
    for (int k0 = 0; k0 < K; k0 += 64) {
        #pragma unroll
        for (int i = 0; i < 4; ++i) {
            int u = (wave * 4 + i) * 64 + lane;
            int r = u >> 3, p = u & 7;
            int c = p ^ (r & 7);
            GLDS16(A  + (size_t)(row0 + r) * K + (k0 + c * 8), &sA[(wave * 4 + i) * 512]);
            GLDS16(BT + (size_t)(col0 + r) * K + (k0 + c * 8), &sB[(wave * 4 + i) * 512]);
        }
        asm volatile("s_waitcnt vmcnt(0)" ::: "memory");
        __syncthreads();
        #pragma unroll
        for (int kk = 0; kk < 64; kk += 32) {
            bf16x8 afr[4], bfr[4];
            #pragma unroll
            for (int mt = 0; mt < 4; ++mt) {
                int r = wm * 64 + mt * 16 + (lane & 15);
                int c = (kk >> 3) + q;
                afr[mt] = *(const bf16x8*)&sA[(r * 8 + (c ^ (r & 7))) * 8];
            }
            #pragma unroll
            for (int nt = 0; nt < 4; ++nt) {
                int r = wn * 64 + nt * 16 + (lane & 15);
                int c = (kk >> 3) + q;
                bfr[nt] = *(const bf16x8*)&sB[(r * 8 + (c ^ (r & 7))) * 8];
            }
            #pragma unroll
            for (int mt = 0; mt < 4; ++mt)
                #pragma unroll
                for (int nt = 0; nt < 4; ++nt)
                    acc[mt][nt] = MFMA16(afr[mt], bfr[nt], acc[mt][nt]);
        }
        __syncthreads();
    }
}

// ----------------------------------------------- readout GEMM (plain, fp32 C)
__global__ __launch_bounds__(256) void k_gemm_ro(
    const bf16* __restrict__ A, const bf16* __restrict__ BT,
    float* __restrict__ Cout)
{
    __shared__ __align__(16) bf16 sm[16384];
    bf16* sA = sm;
    bf16* sB = sm + 8192;
    const int tid = threadIdx.x;
    const int lane = tid & 63, wave = tid >> 6, q = lane >> 4;
    const int wm = wave & 1, wn = wave >> 1;
    const int row0 = blockIdx.y * 128, col0 = blockIdx.x * 128;

    floatx4 acc[4][4] = {};
    gemm_mainloop(A, BT, RDIM, row0, col0, lane, wave, wm, wn, q, sA, sB, acc);

    #pragma unroll
    for (int mt = 0; mt < 4; ++mt)
        #pragma unroll
        for (int nt = 0; nt < 4; ++nt) {
            int col = col0 + wn * 64 + nt * 16 + (lane & 15);
            #pragma unroll
            for (int i = 0; i < 4; ++i) {
                int row = row0 + wm * 64 + mt * 16 + q * 4 + i;
                Cout[(size_t)row * EMB_DIM + col] = acc[mt][nt][i];
            }
        }
}

// ------------------------------------------------------- InstanceNorm + leaky
__global__ __launch_bounds__(256) void k_instnorm(
    const float* __restrict__ emb, float* __restrict__ out)
{
    int row = blockIdx.x, tid = threadIdx.x;
    int lane = tid & 63, wave = tid >> 6;
    __shared__ float sS[4], sQ[4];
    float v0 = emb[(size_t)row * EMB_DIM + tid];
    float v1 = emb[(size_t)row * EMB_DIM + 256 + tid];
    float s = v0 + v1, q = v0 * v0 + v1 * v1;
    #pragma unroll
    for (int off = 32; off; off >>= 1) {
        s += __shfl_down(s, off);
        q += __shfl_down(q, off);
    }
    if (lane == 0) { sS[wave] = s; sQ[wave] = q; }
    __syncthreads();
    float S = sS[0] + sS[1] + sS[2] + sS[3];
    float Q = sQ[0] + sQ[1] + sQ[2] + sQ[3];
    float mu = S * (1.f / 512.f);
    float var = Q * (1.f / 512.f) - mu * mu;
    float rs = rsqrtf(var + EPS_F);
    float o0 = (v0 - mu) * rs; o0 = (o0 >= 0.f) ? o0 : SLOPE_F * o0;
    float o1 = (v1 - mu) * rs; o1 = (o1 >= 0.f) ? o1 : SLOPE_F * o1;
    out[(size_t)row * EMB_DIM + tid]       = o0;
    out[(size_t)row * EMB_DIM + 256 + tid] = o1;
}

// ----------------------------------------------------------------- launcher
extern "C" void kernel_launch(void* const* d_in, const int* in_sizes, int n_in,
                              void* d_out, int out_size, void* d_ws, size_t ws_size,
                              hipStream_t stream) {
    const float* x    = (const float*)d_in[0];
    const float* ew   = (const float*)d_in[1];
    const float* W1   = (const float*)d_in[2];
    const float* W2   = (const float*)d_in[3];
    const float* Wemb = (const float*)d_in[4];
    const float* a1   = (const float*)d_in[5];
    const float* g1   = (const float*)d_in[6];
    const float* b1   = (const float*)d_in[7];
    const float* a2   = (const float*)d_in[8];
    const float* g2   = (const float*)d_in[9];
    const float* b2   = (const float*)d_in[10];
    const int* esrc   = (const int*)d_in[11];
    const int* edst   = (const int*)d_in[12];
    float* out = (float*)d_out;

    char* ws = (char*)d_ws;
    const size_t MB = 1024ull * 1024ull;
    bf16*  adjb   = (bf16*)(ws);                       // 8 MB
    float* scl_o  = (float*)(ws + 8 * MB);             // 256 KB
    bf16*  Rb     = (bf16*)(ws + 9 * MB);              // 3.5 MB
    bf16*  W1T    = (bf16*)(ws + 13 * MB);             // 1 MB
    bf16*  W2T    = (bf16*)(ws + 14 * MB);             // 0.5 MB
    bf16*  WembT  = (bf16*)(ws + 15 * MB);             // 1.75 MB
    float* emb    = (float*)(ws + 17 * MB);            // 2 MB
    bf16*  axs1   = (bf16*)(ws + 20 * MB);             // 64 MB

    k_graph_build<<<N_GRAPHS, 256, 0, stream>>>(esrc, edst, ew, adjb, scl_o);
    k_transpose<<<2048, 256, 0, stream>>>(W1, W1T, 512, 10);
    k_transpose<<<1024, 256, 0, stream>>>(W2, W2T, 1024, 8);
    k_transpose<<<3584, 256, 0, stream>>>(Wemb, WembT, 1792, 9);

    k_prep_agg1<<<N_GRAPHS * 2, 256, 0, stream>>>(x, scl_o, adjb, axs1, Rb);

    k_fused12<<<N_GRAPHS, 256, 0, stream>>>(
        axs1, W1T, W2T, adjb, scl_o, a1, g1, b1, a2, g2, b2, Rb);

    k_gemm_ro<<<dim3(EMB_DIM / 128, N_GRAPHS / 128), 256, 0, stream>>>(
        Rb, WembT, emb);
    k_instnorm<<<N_GRAPHS, 256, 0, stream>>>(emb, out);

    (void)in_sizes; (void)n_in; (void)out_size; (void)ws_size;
}

// Round 5
// 491.653 us; speedup vs baseline: 1.2337x; 1.2337x over previous
//
#include <hip/hip_runtime.h>
#include <hip/hip_bf16.h>
#include <stdint.h>

#define N_NODES   65536
#define N_GRAPHS  1024
#define N_EDGES   1048576
#define IN_FEATS  512
#define HIDDEN    1024
#define H4        256
#define EMB_DIM   512
#define RDIM      1792   // 512 + 1024 + 256
#define EPS_F     1e-5f
#define SLOPE_F   0.01f

typedef __bf16 bf16;
typedef __bf16 bf16x8 __attribute__((ext_vector_type(8)));
typedef float  floatx4 __attribute__((ext_vector_type(4)));

#define GLDS16(gp, lp) __builtin_amdgcn_global_load_lds( \
    (const __attribute__((address_space(1))) void*)(gp), \
    (__attribute__((address_space(3))) void*)(lp), 16, 0, 0)

#define MFMA16(a, b, c) __builtin_amdgcn_mfma_f32_16x16x32_bf16((a), (b), (c), 0, 0, 0)

// -------------------------------------------- fused edge pass, per graph
__global__ __launch_bounds__(256) void k_graph_build(
    const int* __restrict__ src, const int* __restrict__ dst,
    const float* __restrict__ ew,
    bf16* __restrict__ adjb, float* __restrict__ scl_o)
{
    __shared__ float sAdj[4096];
    __shared__ float sDegO[64], sDegI[64];
    int g = blockIdx.x, tid = threadIdx.x;
    for (int i = tid; i < 4096; i += 256) sAdj[i] = 0.f;
    if (tid < 64) { sDegO[tid] = 0.f; sDegI[tid] = 0.f; }
    __syncthreads();
    int e0 = g * 1024;
    #pragma unroll
    for (int i = 0; i < 4; ++i) {
        int e = e0 + i * 256 + tid;
        int s = src[e] & 63, d = dst[e] & 63;
        atomicAdd(&sAdj[(d << 6) | s], ew[e]);
        atomicAdd(&sDegO[s], 1.f);
        atomicAdd(&sDegI[d], 1.f);
    }
    __syncthreads();
    if (tid < 64) scl_o[g * 64 + tid] = rsqrtf(fmaxf(sDegO[tid], 1.f));
    bf16* ag = adjb + ((size_t)g << 12);
    for (int i = tid; i < 4096; i += 256) {
        float si = rsqrtf(fmaxf(sDegI[i >> 6], 1.f));
        ag[i] = (bf16)(sAdj[i] * si);
    }
}

// all three weight transposes in one launch
__global__ __launch_bounds__(256) void k_transpose_all(
    const float* __restrict__ W1, const float* __restrict__ W2,
    const float* __restrict__ Wemb,
    bf16* __restrict__ W1T, bf16* __restrict__ W2T, bf16* __restrict__ WembT)
{
    int idx = blockIdx.x * 256 + threadIdx.x;
    if (idx < 524288) {                       // W1: 512x1024
        int n = idx & 1023, k = idx >> 10;
        W1T[(size_t)n * 512 + k] = (bf16)W1[idx];
    } else if (idx < 786432) {                // W2: 1024x256
        int i = idx - 524288;
        int n = i & 255, k = i >> 8;
        W2T[(size_t)n * 1024 + k] = (bf16)W2[i];
    } else {                                  // Wemb: 1792x512
        int i = idx - 786432;
        int n = i & 511, k = i >> 9;
        WembT[(size_t)n * 1792 + k] = (bf16)Wemb[i];
    }
}

// -------------------------------------- fused prep + agg layer 1 (2 blk/graph)
__global__ __launch_bounds__(256) void k_prep_agg1(
    const float* __restrict__ x, const float* __restrict__ so,
    const bf16* __restrict__ adjb,
    bf16* __restrict__ axs1, bf16* __restrict__ Rb)
{
    __shared__ __align__(16) bf16 sOut[64 * 264];
    __shared__ float sSo[64];
    int g = blockIdx.x >> 1, half = blockIdx.x & 1;
    int tid = threadIdx.x, lane = tid & 63, wave = tid >> 6, q = lane >> 4;
    if (tid < 64) sSo[tid] = so[g * 64 + tid];
    const float* xg = x + (size_t)g * 64 * IN_FEATS + half * 256;
    const bf16* ag = adjb + ((size_t)g << 12);

    bf16x8 af[4][2];
    #pragma unroll
    for (int mt = 0; mt < 4; ++mt)
        #pragma unroll
        for (int kk = 0; kk < 2; ++kk)
            af[mt][kk] = *(const bf16x8*)&ag[(mt * 16 + (lane & 15)) * 64 + kk * 32 + q * 8];
    __syncthreads();
    float sov[2][8];
    #pragma unroll
    for (int kk = 0; kk < 2; ++kk)
        #pragma unroll
        for (int j = 0; j < 8; ++j) sov[kk][j] = sSo[kk * 32 + q * 8 + j];

    #pragma unroll
    for (int nt = 0; nt < 4; ++nt) {
        int cl = wave * 64 + nt * 16 + (lane & 15);
        floatx4 acc[4] = {};
        float r0 = 0.f;
        #pragma unroll
        for (int kk = 0; kk < 2; ++kk) {
            bf16x8 bfrag;
            #pragma unroll
            for (int j = 0; j < 8; ++j) {
                float v = xg[(size_t)(kk * 32 + q * 8 + j) * IN_FEATS + cl];
                r0 += v;
                bfrag[j] = (bf16)(v * sov[kk][j]);
            }
            #pragma unroll
            for (int mt = 0; mt < 4; ++mt)
                acc[mt] = MFMA16(af[mt][kk], bfrag, acc[mt]);
        }
        r0 += __shfl_xor(r0, 16);
        r0 += __shfl_xor(r0, 32);
        if (lane < 16) Rb[(size_t)g * RDIM + half * 256 + cl] = (bf16)(r0 * (1.f / 64.f));
        #pragma unroll
        for (int mt = 0; mt < 4; ++mt)
            #pragma unroll
            for (int i = 0; i < 4; ++i)
                sOut[(mt * 16 + q * 4 + i) * 264 + cl] = (bf16)acc[mt][i];
    }
    __syncthreads();
    #pragma unroll
    for (int it = 0; it < 8; ++it) {
        int idx = it * 256 + tid;
        int d = idx >> 5, c8 = idx & 31;
        *(bf16x8*)&axs1[(size_t)(g * 64 + d) * IN_FEATS + half * 256 + c8 * 8] =
            *(const bf16x8*)&sOut[d * 264 + c8 * 8];
    }
}

// ----------------------------------------------------- shared GEMM main loop
// 128x128 tile, BK=64, XOR-swizzled LDS staging via global_load_lds width=16.
__device__ __forceinline__ void gemm_mainloop(
    const bf16* __restrict__ A, const bf16* __restrict__ BT, int K,
    int row0, int col0, int lane, int wave, int wm, int wn, int q,
    bf16* sA, bf16* sB, floatx4 (&acc)[4][4])
{
    for (int k0 = 0; k0 < K; k0 += 64) {
        #pragma unroll
        for (int i = 0; i < 4; ++i) {
            int u = (wave * 4 + i) * 64 + lane;
            int r = u >> 3, p = u & 7;
            int c = p ^ (r & 7);
            GLDS16(A  + (size_t)(row0 + r) * K + (k0 + c * 8), &sA[(wave * 4 + i) * 512]);
            GLDS16(BT + (size_t)(col0 + r) * K + (k0 + c * 8), &sB[(wave * 4 + i) * 512]);
        }
        asm volatile("s_waitcnt vmcnt(0)" ::: "memory");
        __syncthreads();
        #pragma unroll
        for (int kk = 0; kk < 64; kk += 32) {
            bf16x8 afr[4], bfr[4];
            #pragma unroll
            for (int mt = 0; mt < 4; ++mt) {
                int r = wm * 64 + mt * 16 + (lane & 15);
                int c = (kk >> 3) + q;
                afr[mt] = *(const bf16x8*)&sA[(r * 8 + (c ^ (r & 7))) * 8];
            }
            #pragma unroll
            for (int nt = 0; nt < 4; ++nt) {
                int r = wn * 64 + nt * 16 + (lane & 15);
                int c = (kk >> 3) + q;
                bfr[nt] = *(const bf16x8*)&sB[(r * 8 + (c ^ (r & 7))) * 8];
            }
            #pragma unroll
            for (int mt = 0; mt < 4; ++mt)
                #pragma unroll
                for (int nt = 0; nt < 4; ++nt)
                    acc[mt][nt] = MFMA16(afr[mt], bfr[nt], acc[mt][nt]);
        }
        __syncthreads();
    }
}

__device__ __forceinline__ void swizzle_block(int cb, int& bx, int& by)
{
    int b = blockIdx.y * gridDim.x + blockIdx.x;
    int xcd = b & 7, t = b >> 3;
    bx = t % cb;
    by = (t / cb) * 8 + xcd;
}

// ---------------- GEMM1: axs1@W1 + GraphNorm + leaky + r1 + xs2(scaled) store
__global__ __launch_bounds__(256) void k_gemm1_f(
    const bf16* __restrict__ A, const bf16* __restrict__ BT,
    const float* __restrict__ alpha, const float* __restrict__ gamma,
    const float* __restrict__ beta,
    const float* __restrict__ so,
    bf16* __restrict__ xs2, bf16* __restrict__ Rb)
{
    __shared__ __align__(16) bf16 sm[128 * 136];
    __shared__ float sSo[128];
    bf16* sA = sm;
    bf16* sB = sm + 8192;
    const int tid = threadIdx.x;
    const int lane = tid & 63, wave = tid >> 6, q = lane >> 4;
    const int wm = wave & 1, wn = wave >> 1;
    int bx, by; swizzle_block(gridDim.x, bx, by);
    const int row0 = by * 128, col0 = bx * 128;

    if (tid < 128) sSo[tid] = so[row0 + tid];

    floatx4 acc[4][4] = {};
    gemm_mainloop(A, BT, IN_FEATS, row0, col0, lane, wave, wm, wn, q, sA, sB, acc);

    const int gw = by * 2 + wm;
    bf16* sOut = sm;                                // [128 r][136 pitch]
    #pragma unroll
    for (int nt = 0; nt < 4; ++nt) {
        int cl = wn * 64 + nt * 16 + (lane & 15);
        int colg = col0 + cl;
        float lsum = 0.f;
        #pragma unroll
        for (int mt = 0; mt < 4; ++mt)
            #pragma unroll
            for (int i = 0; i < 4; ++i) lsum += acc[mt][nt][i];
        lsum += __shfl_xor(lsum, 16);
        lsum += __shfl_xor(lsum, 32);
        float am = alpha[colg] * (lsum * (1.f / 64.f));
        float gm = gamma[colg], bt = beta[colg];
        float sub[4][4], qv = 0.f;
        #pragma unroll
        for (int mt = 0; mt < 4; ++mt)
            #pragma unroll
            for (int i = 0; i < 4; ++i) {
                float d = acc[mt][nt][i] - am;
                sub[mt][i] = d; qv += d * d;
            }
        qv += __shfl_xor(qv, 16);
        qv += __shfl_xor(qv, 32);
        float rs = rsqrtf(qv * (1.f / 64.f) + EPS_F);
        float rsum = 0.f;
        #pragma unroll
        for (int mt = 0; mt < 4; ++mt)
            #pragma unroll
            for (int i = 0; i < 4; ++i) {
                float o = gm * sub[mt][i] * rs + bt;
                o = (o >= 0.f) ? o : SLOPE_F * o;
                rsum += o;
                int r = wm * 64 + mt * 16 + q * 4 + i;
                sOut[r * 136 + cl] = (bf16)(o * sSo[r]);
            }
        rsum += __shfl_xor(rsum, 16);
        rsum += __shfl_xor(rsum, 32);
        if (lane < 16)
            Rb[(size_t)gw * RDIM + 512 + colg] = (bf16)(rsum * (1.f / 64.f));
    }
    __syncthreads();
    #pragma unroll
    for (int it = 0; it < 8; ++it) {
        int idx = it * 256 + tid;
        int r = idx >> 4, c8 = idx & 15;
        *(bf16x8*)&xs2[(size_t)(row0 + r) * HIDDEN + col0 + c8 * 8] =
            *(const bf16x8*)&sOut[r * 136 + c8 * 8];
    }
}

// ---- GEMM2: one graph per block (BM=64, BN=256=all of H4), K=1024.
// xs2[g]@W2 -> in-LDS transpose -> wave-local agg (adj@y) -> GN2 + r2 -> Rb.
// A read exactly once from HBM; B (W2T, 0.5 MB) stays L2-resident.
__global__ __launch_bounds__(256) void k_gemm2_f(
    const bf16* __restrict__ A, const bf16* __restrict__ BT,
    const bf16* __restrict__ adjb,
    const float* __restrict__ alpha, const float* __restrict__ gamma,
    const float* __restrict__ beta,
    bf16* __restrict__ Rb)
{
    __shared__ __align__(16) bf16 sm[20480];     // 40 KB: sA 8K + sB 32K
    bf16* sA = sm;          // [64 r][8 units], unit c at c^(r&7)
    bf16* sB = sm + 4096;   // [256 r][8 units], unit c at c^(r&7)
    const int g = blockIdx.x, tid = threadIdx.x;
    const int lane = tid & 63, wave = tid >> 6, q = lane >> 4, l15 = lane & 15;

    floatx4 acc[4][4] = {};
    const bf16* Ag = A + ((size_t)g << 6) * HIDDEN;

    for (int k0 = 0; k0 < HIDDEN; k0 += 64) {
        {   // stage A: 512 units, 2/thread
            #pragma unroll
            for (int i = 0; i < 2; ++i) {
                int u = i * 256 + tid;
                int r = u >> 3, c = (u & 7) ^ (r & 7);
                GLDS16(Ag + (size_t)r * HIDDEN + (k0 + c * 8), &sA[(i * 256 + wave * 64) * 8]);
            }
            // stage B: 2048 units, 8/thread
            #pragma unroll
            for (int i = 0; i < 8; ++i) {
                int u = i * 256 + tid;
                int r = u >> 3, c = (u & 7) ^ (r & 7);
                GLDS16(BT + (size_t)r * HIDDEN + (k0 + c * 8), &sB[(i * 256 + wave * 64) * 8]);
            }
        }
        asm volatile("s_waitcnt vmcnt(0)" ::: "memory");
        __syncthreads();
        #pragma unroll
        for (int kk = 0; kk < 64; kk += 32) {
            bf16x8 afr[4], bfr[4];
            #pragma unroll
            for (int mt = 0; mt < 4; ++mt) {
                int r = mt * 16 + l15;
                int c = (kk >> 3) + q;
                afr[mt] = *(const bf16x8*)&sA[(r * 8 + (c ^ (r & 7))) * 8];
            }
            #pragma unroll
            for (int nt = 0; nt < 4; ++nt) {
                int r = wave * 64 + nt * 16 + l15;
                int c = (kk >> 3) + q;
                bfr[nt] = *(const bf16x8*)&sB[(r * 8 + (c ^ (r & 7))) * 8];
            }
            #pragma unroll
            for (int mt = 0; mt < 4; ++mt)
                #pragma unroll
                for (int nt = 0; nt < 4; ++nt)
                    acc[mt][nt] = MFMA16(afr[mt], bfr[nt], acc[mt][nt]);
        }
        __syncthreads();
    }

    // transpose wave's 64x64 quadrant into LDS [col][node pitch 68]
    bf16* sT = sm + wave * (64 * 68);
    #pragma unroll
    for (int nt = 0; nt < 4; ++nt) {
        int cl = nt * 16 + l15;
        #pragma unroll
        for (int mt = 0; mt < 4; ++mt)
            #pragma unroll
            for (int i = 0; i < 4; ++i)
                sT[cl * 68 + mt * 16 + q * 4 + i] = (bf16)acc[mt][nt][i];
    }
    asm volatile("s_waitcnt lgkmcnt(0)" ::: "memory");   // wave-local LDS RAW

    // h2agg = adj_g @ y (wave's 64-col slice)
    const bf16* ag = adjb + ((size_t)g << 12);
    floatx4 a2[4][4] = {};
    #pragma unroll
    for (int kk = 0; kk < 2; ++kk) {
        bf16x8 afr[4], bfr[4];
        #pragma unroll
        for (int mt = 0; mt < 4; ++mt)
            afr[mt] = *(const bf16x8*)&ag[(mt * 16 + l15) * 64 + kk * 32 + q * 8];
        #pragma unroll
        for (int nt = 0; nt < 4; ++nt)
            bfr[nt] = *(const bf16x8*)&sT[(nt * 16 + l15) * 68 + kk * 32 + q * 8];
        #pragma unroll
        for (int mt = 0; mt < 4; ++mt)
            #pragma unroll
            for (int nt = 0; nt < 4; ++nt)
                a2[mt][nt] = MFMA16(afr[mt], bfr[nt], a2[mt][nt]);
    }

    // GraphNorm2 + leaky + r2
    #pragma unroll
    for (int nt = 0; nt < 4; ++nt) {
        int colg = wave * 64 + nt * 16 + l15;            // 0..255
        float lsum = 0.f;
        #pragma unroll
        for (int mt = 0; mt < 4; ++mt)
            #pragma unroll
            for (int i = 0; i < 4; ++i) lsum += a2[mt][nt][i];
        lsum += __shfl_xor(lsum, 16);
        lsum += __shfl_xor(lsum, 32);
        float am = alpha[colg] * (lsum * (1.f / 64.f));
        float gm = gamma[colg], bt = beta[colg];
        float sub[4][4], qv = 0.f;
        #pragma unroll
        for (int mt = 0; mt < 4; ++mt)
            #pragma unroll
            for (int i = 0; i < 4; ++i) {
                float d = a2[mt][nt][i] - am;
                sub[mt][i] = d; qv += d * d;
            }
        qv += __shfl_xor(qv, 16);
        qv += __shfl_xor(qv, 32);
        float rs = rsqrtf(qv * (1.f / 64.f) + EPS_F);
        float rsum = 0.f;
        #pragma unroll
        for (int mt = 0; mt < 4; ++mt)
            #pragma unroll
            for (int i = 0; i < 4; ++i) {
                float o = gm * sub[mt][i] * rs + bt;
                rsum += (o >= 0.f) ? o : SLOPE_F * o;
            }
        rsum += __shfl_xor(rsum, 16);
        rsum += __shfl_xor(rsum, 32);
        if (lane < 16)
            Rb[(size_t)g * RDIM + 1536 + colg] = (bf16)(rsum * (1.f / 64.f));
    }
}

// ----------------------------------------------- readout GEMM (plain, fp32 C)
__global__ __launch_bounds__(256) void k_gemm_ro(
    const bf16* __restrict__ A, const bf16* __restrict__ BT,
    float* __restrict__ Cout)
{
    __shared__ __align__(16) bf16 sm[16384];
    bf16* sA = sm;
    bf16* sB = sm + 8192;
    const int tid = threadIdx.x;
    const int lane = tid & 63, wave = tid >> 6, q = lane >> 4;
    const int wm = wave & 1, wn = wave >> 1;
    const int row0 = blockIdx.y * 128, col0 = blockIdx.x * 128;

    floatx4 acc[4][4] = {};
    gemm_mainloop(A, BT, RDIM, row0, col0, lane, wave, wm, wn, q, sA, sB, acc);

    #pragma unroll
    for (int mt = 0; mt < 4; ++mt)
        #pragma unroll
        for (int nt = 0; nt < 4; ++nt) {
            int col = col0 + wn * 64 + nt * 16 + (lane & 15);
            #pragma unroll
            for (int i = 0; i < 4; ++i) {
                int row = row0 + wm * 64 + mt * 16 + q * 4 + i;
                Cout[(size_t)row * EMB_DIM + col] = acc[mt][nt][i];
            }
        }
}

// ------------------------------------------------------- InstanceNorm + leaky
__global__ __launch_bounds__(256) void k_instnorm(
    const float* __restrict__ emb, float* __restrict__ out)
{
    int row = blockIdx.x, tid = threadIdx.x;
    int lane = tid & 63, wave = tid >> 6;
    __shared__ float sS[4], sQ[4];
    float v0 = emb[(size_t)row * EMB_DIM + tid];
    float v1 = emb[(size_t)row * EMB_DIM + 256 + tid];
    float s = v0 + v1, q = v0 * v0 + v1 * v1;
    #pragma unroll
    for (int off = 32; off; off >>= 1) {
        s += __shfl_down(s, off);
        q += __shfl_down(q, off);
    }
    if (lane == 0) { sS[wave] = s; sQ[wave] = q; }
    __syncthreads();
    float S = sS[0] + sS[1] + sS[2] + sS[3];
    float Q = sQ[0] + sQ[1] + sQ[2] + sQ[3];
    float mu = S * (1.f / 512.f);
    float var = Q * (1.f / 512.f) - mu * mu;
    float rs = rsqrtf(var + EPS_F);
    float o0 = (v0 - mu) * rs; o0 = (o0 >= 0.f) ? o0 : SLOPE_F * o0;
    float o1 = (v1 - mu) * rs; o1 = (o1 >= 0.f) ? o1 : SLOPE_F * o1;
    out[(size_t)row * EMB_DIM + tid]       = o0;
    out[(size_t)row * EMB_DIM + 256 + tid] = o1;
}

// ----------------------------------------------------------------- launcher
extern "C" void kernel_launch(void* const* d_in, const int* in_sizes, int n_in,
                              void* d_out, int out_size, void* d_ws, size_t ws_size,
                              hipStream_t stream) {
    const float* x    = (const float*)d_in[0];
    const float* ew   = (const float*)d_in[1];
    const float* W1   = (const float*)d_in[2];
    const float* W2   = (const float*)d_in[3];
    const float* Wemb = (const float*)d_in[4];
    const float* a1   = (const float*)d_in[5];
    const float* g1   = (const float*)d_in[6];
    const float* b1   = (const float*)d_in[7];
    const float* a2   = (const float*)d_in[8];
    const float* g2   = (const float*)d_in[9];
    const float* b2   = (const float*)d_in[10];
    const int* esrc   = (const int*)d_in[11];
    const int* edst   = (const int*)d_in[12];
    float* out = (float*)d_out;

    char* ws = (char*)d_ws;
    const size_t MB = 1024ull * 1024ull;
    bf16*  adjb   = (bf16*)(ws);                       // 8 MB
    float* scl_o  = (float*)(ws + 8 * MB);             // 256 KB
    bf16*  Rb     = (bf16*)(ws + 9 * MB);              // 3.5 MB
    bf16*  W1T    = (bf16*)(ws + 13 * MB);             // 1 MB
    bf16*  W2T    = (bf16*)(ws + 14 * MB);             // 0.5 MB
    bf16*  WembT  = (bf16*)(ws + 15 * MB);             // 1.75 MB
    float* emb    = (float*)(ws + 17 * MB);            // 2 MB
    bf16*  axs1   = (bf16*)(ws + 20 * MB);             // 64 MB
    bf16*  xs2    = (bf16*)(ws + 84 * MB);             // 128 MB (ends 212M)

    k_graph_build<<<N_GRAPHS, 256, 0, stream>>>(esrc, edst, ew, adjb, scl_o);
    k_transpose_all<<<6656, 256, 0, stream>>>(W1, W2, Wemb, W1T, W2T, WembT);

    k_prep_agg1<<<N_GRAPHS * 2, 256, 0, stream>>>(x, scl_o, adjb, axs1, Rb);

    k_gemm1_f<<<dim3(HIDDEN / 128, N_NODES / 128), 256, 0, stream>>>(
        axs1, W1T, a1, g1, b1, scl_o, xs2, Rb);
    k_gemm2_f<<<N_GRAPHS, 256, 0, stream>>>(
        xs2, W2T, adjb, a2, g2, b2, Rb);
    k_gemm_ro<<<dim3(EMB_DIM / 128, N_GRAPHS / 128), 256, 0, stream>>>(
        Rb, WembT, emb);
    k_instnorm<<<N_GRAPHS, 256, 0, stream>>>(emb, out);

    (void)in_sizes; (void)n_in; (void)out_size; (void)ws_size;
}